// Round 6
// baseline (122.043 us; speedup 1.0000x reference)
//
#include <hip/hip_runtime.h>
#include <hip/hip_bf16.h>
#include <stdint.h>

#define BATCH    512
#define IN_DIM   256
#define OUT_DIM  256
#define COND_DIM 128
#define HIDDEN   128
#define W2_COLS  65792      // 256*257
#define H_STRIDE 132
#define PLANE_SZ 65536      // shorts per transposed bf16 plane [o][i]
#define OUT_ELEMS (BATCH * OUT_DIM)

// workspace layout (shorts unless noted):
//   [0, 131*PLANE_SZ)                     : transposed bf16 planes
//   XBF_OFF  = 131*PLANE_SZ               : bf16 x      (BATCH*IN_DIM shorts)
//   HBF_OFF  = XBF_OFF + BATCH*IN_DIM     : bf16 h      (BATCH*HIDDEN shorts)
//   H_OFF    = HBF_OFF + BATCH*HIDDEN     : f32 h       (BATCH*H_STRIDE+8 floats)
#define XBF_OFF  ((size_t)131 * PLANE_SZ)
#define HBF_OFF  (XBF_OFF + (size_t)BATCH * IN_DIM)
#define H_OFF    (HBF_OFF + (size_t)BATCH * HIDDEN)     // short offset; *2 = byte, /2 = float idx

typedef __attribute__((ext_vector_type(8))) short bf16x8;
typedef __attribute__((ext_vector_type(4))) float f32x4;

static __device__ __forceinline__ unsigned short f2bf(float f) {
    union { float f; unsigned int u; } v; v.f = f;
    unsigned int r = v.u + 0x7FFFu + ((v.u >> 16) & 1u);  // RNE
    return (unsigned short)(r >> 16);
}
static __device__ __forceinline__ unsigned int pack2(float a, float b) {
    return (unsigned int)f2bf(a) | ((unsigned int)f2bf(b) << 16);
}

template<int N>
static __device__ __forceinline__ void wait_vmcnt() {
    if constexpr (N == 0)      asm volatile("s_waitcnt vmcnt(0)" ::: "memory");
    else if constexpr (N == 2) asm volatile("s_waitcnt vmcnt(2)" ::: "memory");
    else if constexpr (N == 4) asm volatile("s_waitcnt vmcnt(4)" ::: "memory");
    else if constexpr (N == 6) asm volatile("s_waitcnt vmcnt(6)" ::: "memory");
    else                       asm volatile("s_waitcnt vmcnt(8)" ::: "memory");
}

// ---------------- prep: convert/transpose planes + x,h + out-init ----------
// grid: [0,2080) w2/b2w/bw plane tiles; [2080,2088) bias-col tiles;
//       [2088,2104) x convert; [2104,2360) h compute (2 rows/block);
//       [2360,2488) out init = base_bias + b2_bias
__global__ __launch_bounds__(256)
void hyper_prep_kernel(const float* __restrict__ x,
                       const float* __restrict__ cond,
                       const float* __restrict__ base_weight,
                       const float* __restrict__ base_bias,
                       const float* __restrict__ w1,
                       const float* __restrict__ b1,
                       const float* __restrict__ w2,
                       const float* __restrict__ b2,
                       unsigned short* __restrict__ wt,
                       unsigned short* __restrict__ gxbf,
                       unsigned short* __restrict__ ghbf,
                       float* __restrict__ gh,
                       float* __restrict__ out) {
    const int bx = blockIdx.x;
    const int t  = threadIdx.x;
    if (bx < 2088) {
        int p, it, ot; const float* src; int rstride;
        if (bx < 2080) {
            p = bx >> 4; int sub = bx & 15; it = sub >> 2; ot = sub & 3;
            src = (p < 128) ? (w2 + (size_t)p * W2_COLS) : (p == 128 ? b2 : base_weight);
            rstride = OUT_DIM;
        } else {
            p = 130; int sub = bx - 2080; it = sub >> 2; ot = sub & 3;   // it 0..1 (k<128)
            src = w2 + 65536; rstride = W2_COLS;
        }
        int o  = ot * 64 + (t & 63);
        int i0 = it * 64 + (t >> 6) * 16;
        unsigned int vv[8];
        #pragma unroll
        for (int r = 0; r < 8; ++r) {
            float a = src[(size_t)(i0 + 2 * r)     * rstride + o];
            float b = src[(size_t)(i0 + 2 * r + 1) * rstride + o];
            vv[r] = pack2(a, b);
        }
        unsigned int* dst = (unsigned int*)(wt + (size_t)p * PLANE_SZ + (size_t)o * 256 + i0);
        *(uint4*)dst       = *(uint4*)&vv[0];
        *(uint4*)(dst + 4) = *(uint4*)&vv[4];
    } else if (bx < 2104) {
        int base = (bx - 2088) * 8192 + t * 32;
        #pragma unroll
        for (int g = 0; g < 4; ++g) {
            const float4* s4 = (const float4*)(x + base + g * 8);
            float4 a = s4[0], b = s4[1];
            unsigned int vv[4] = { pack2(a.x, a.y), pack2(a.z, a.w),
                                   pack2(b.x, b.y), pack2(b.z, b.w) };
            *(uint4*)(gxbf + base + g * 8) = *(uint4*)vv;
        }
    } else if (bx < 2360) {
        __shared__ float c[2][COND_DIM];
        int bb = t >> 7, k = t & 127;
        int b  = (bx - 2104) * 2 + bb;
        c[bb][k] = cond[b * COND_DIM + k];
        __syncthreads();
        float acc = b1[k];
        #pragma unroll 8
        for (int i = 0; i < COND_DIM; ++i)
            acc += c[bb][i] * w1[i * HIDDEN + k];
        acc = fmaxf(acc, 0.0f);
        gh[b * H_STRIDE + k] = acc;
        ghbf[b * HIDDEN + k] = f2bf(acc);
        if (k < 4) gh[b * H_STRIDE + 128 + k] = 1.0f;
    } else {
        // out init: out[b,o] = base_bias[o] + b2[65536+o]   (float4 granular)
        int i = (bx - 2360) * 256 + t;                 // float4 index, 32768 total
        int o = (i & 63) * 4;
        float4 bb = *(const float4*)(base_bias + o);
        float4 c2 = *(const float4*)(b2 + 65536 + o);
        float4 a;
        a.x = bb.x + c2.x; a.y = bb.y + c2.y; a.z = bb.z + c2.z; a.w = bb.w + c2.w;
        ((float4*)out)[i] = a;
    }
}

// ---------------- main: split-K MFMA GEMM, deep counted-vmcnt pipeline -----
// 4 waves (256 thr), 64x64 tile, 6 LDS buffers, DMA issued 5 steps ahead
// (10 loads in flight), steady s_waitcnt vmcnt(8), tail 6/4/2/0, ONE
// s_barrier per step. Refill target buffer (s+5)%6 == (s-1)%6 was consumed
// at step s-1; barrier(s) separates. Epilogue: f32 atomics into out.
template<int NSLABS>
static __device__ __forceinline__ void run_gemm(
    int nplanes, int p0, const unsigned short* asrc, int astride,
    const unsigned short* __restrict__ wt, float* __restrict__ out,
    int b0, int o0, int t,
    unsigned short (*B_lds)[64 * 64], const float* h_s)
{
    constexpr int LOG2S = (NSLABS == 4) ? 2 : 1;
    const int lane = t & 63, wave = t >> 6;
    const int wm = wave >> 1, wn = wave & 1;
    const int qg = lane >> 4, ncol = lane & 15;

    const int drow = lane >> 3;                  // 0..7
    const int dcol = ((lane & 7) ^ drow) * 8;    // swizzled k-block (shorts)
    const int nsteps = nplanes * NSLABS;

    auto dmaB = [&](int s, int buf) {
        const int plane = p0 + (s >> LOG2S);
        const int i0    = (s & (NSLABS - 1)) * 64;
        const unsigned short* gp = wt + (size_t)plane * PLANE_SZ
            + (size_t)(o0 + wave * 16 + drow) * 256 + i0 + dcol;
        __builtin_amdgcn_global_load_lds(
            (const __attribute__((address_space(1))) unsigned int*)gp,
            (__attribute__((address_space(3))) unsigned int*)&B_lds[buf][wave * 16 * 64],
            16, 0, 0);
        __builtin_amdgcn_global_load_lds(
            (const __attribute__((address_space(1))) unsigned int*)(gp + 8 * 256),
            (__attribute__((address_space(3))) unsigned int*)&B_lds[buf][(wave * 16 + 8) * 64],
            16, 0, 0);
    };

    // A fragments: loaded once (oldest VMEM ops -> retire before DMA waits)
    bf16x8 xf[NSLABS][2][2];
    #pragma unroll
    for (int sl = 0; sl < NSLABS; ++sl)
        #pragma unroll
        for (int ks = 0; ks < 2; ++ks)
            #pragma unroll
            for (int mf = 0; mf < 2; ++mf)
                xf[sl][ks][mf] = *(const bf16x8*)(asrc
                    + (size_t)(b0 + wm * 32 + mf * 16 + ncol) * astride
                    + sl * 64 + ks * 32 + qg * 8);

    f32x4 acc[2][2] = {};
    f32x4 pacc[2][2];
    float hv[2][4];

    // prologue: fill 5-deep pipeline
    #pragma unroll
    for (int s = 0; s < 5; ++s)
        if (s < nsteps) dmaB(s, s);

    int cur = 0, pre = 5;                        // running buffer indices mod 6

    for (int pl = 0; pl < nplanes; ++pl) {
        #pragma unroll
        for (int sl = 0; sl < NSLABS; ++sl) {
            const int s = pl * NSLABS + sl;

            if (sl == 0) {                       // h scales + pacc reset (pre-wait)
                #pragma unroll
                for (int mf = 0; mf < 2; ++mf)
                    #pragma unroll
                    for (int r = 0; r < 4; ++r)
                        hv[mf][r] = h_s[(wm * 32 + mf * 16 + qg * 4 + r) * 8 + pl];
                #pragma unroll
                for (int a = 0; a < 2; ++a)
                    #pragma unroll
                    for (int bq = 0; bq < 2; ++bq)
                        pacc[a][bq] = (f32x4){0.f, 0.f, 0.f, 0.f};
            }

            // wait only for THIS step's 2 loads (up to 8 newer stay in flight)
            if (s <= nsteps - 5)      wait_vmcnt<8>();
            else if (s == nsteps - 4) wait_vmcnt<6>();
            else if (s == nsteps - 3) wait_vmcnt<4>();
            else if (s == nsteps - 2) wait_vmcnt<2>();
            else                      wait_vmcnt<0>();
            __builtin_amdgcn_s_barrier();
            asm volatile("" ::: "memory");           // no LDS reads above barrier

            __builtin_amdgcn_s_setprio(1);
            #pragma unroll
            for (int ks = 0; ks < 2; ++ks) {
                bf16x8 bfr[2];
                #pragma unroll
                for (int nf = 0; nf < 2; ++nf) {
                    int n = wn * 32 + nf * 16 + ncol;
                    bfr[nf] = *(const bf16x8*)&B_lds[cur][(n * 8 + ((ks * 4 + qg) ^ (n & 7))) * 8];
                }
                #pragma unroll
                for (int mf = 0; mf < 2; ++mf)
                    #pragma unroll
                    for (int nf = 0; nf < 2; ++nf)
                        pacc[mf][nf] = __builtin_amdgcn_mfma_f32_16x16x32_bf16(
                            xf[sl][ks][mf], bfr[nf], pacc[mf][nf], 0, 0, 0);
            }
            __builtin_amdgcn_s_setprio(0);

            if (sl == NSLABS - 1) {              // fold plane into acc with h scale
                #pragma unroll
                for (int mf = 0; mf < 2; ++mf)
                    #pragma unroll
                    for (int nf = 0; nf < 2; ++nf)
                        #pragma unroll
                        for (int r = 0; r < 4; ++r)
                            acc[mf][nf][r] += hv[mf][r] * pacc[mf][nf][r];
            }

            // refill: buffer (s+5)%6 == (s-1)%6, consumed at step s-1;
            // all waves passed barrier(s) after finishing it -> safe
            if (s + 5 < nsteps) dmaB(s + 5, pre);
            cur = (cur == 5) ? 0 : cur + 1;
            pre = (pre == 5) ? 0 : pre + 1;
        }
    }

    // f32 atomic accumulate into out (hardware global_atomic_add_f32)
    #pragma unroll
    for (int mf = 0; mf < 2; ++mf)
        #pragma unroll
        for (int nf = 0; nf < 2; ++nf)
            #pragma unroll
            for (int r = 0; r < 4; ++r) {
                int row = b0 + wm * 32 + mf * 16 + qg * 4 + r;
                int col = o0 + wn * 32 + nf * 16 + ncol;
                unsafeAtomicAdd(&out[(size_t)row * OUT_DIM + col], acc[mf][nf][r]);
            }
}

__global__ __launch_bounds__(256, 3)
void hyper_main_kernel(const unsigned short* __restrict__ wt,
                       const unsigned short* __restrict__ gxbf,
                       const unsigned short* __restrict__ ghbf,
                       const float* __restrict__ gh,
                       float* __restrict__ out) {
    __shared__ __align__(16) unsigned short B_lds[6][64 * 64];   // 48 KB
    __shared__ float h_s[512];                                   // 64 rows x 8 planes

    const int bx    = blockIdx.x;            // 18 * 32 = 576 (single residency round)
    const int chunk = bx >> 5;
    const int rem   = bx & 31;
    const int b0    = (rem >> 2) * 64;
    const int o0    = (rem & 3) * 64;
    const int t     = threadIdx.x;

    const int p0 = (chunk < 16) ? chunk * 8 : (chunk == 16 ? 128 : 130);

    // stage per-plane h scales (chunks 16/17 read 1.0 from gh ones-lanes)
    h_s[t]       = gh[(b0      + (t >> 3)) * H_STRIDE + p0 + (t & 7)];
    h_s[256 + t] = gh[(b0 + 32 + (t >> 3)) * H_STRIDE + p0 + (t & 7)];
    __syncthreads();

    if (chunk < 17)
        run_gemm<4>(chunk < 16 ? 8 : 2, p0, gxbf, IN_DIM,
                    wt, out, b0, o0, t, B_lds, h_s);
    else
        run_gemm<2>(1, p0, ghbf, HIDDEN,
                    wt, out, b0, o0, t, B_lds, h_s);
}

// ---------------- launch ---------------------------------------------------
extern "C" void kernel_launch(void* const* d_in, const int* in_sizes, int n_in,
                              void* d_out, int out_size, void* d_ws, size_t ws_size,
                              hipStream_t stream) {
    const float* x           = (const float*)d_in[0];
    const float* cond        = (const float*)d_in[1];
    const float* base_weight = (const float*)d_in[2];
    const float* base_bias   = (const float*)d_in[3];
    const float* w1          = (const float*)d_in[4];
    const float* b1          = (const float*)d_in[5];
    const float* w2          = (const float*)d_in[6];
    const float* b2          = (const float*)d_in[7];
    float* out = (float*)d_out;

    unsigned short* ws   = (unsigned short*)d_ws;   // planes + x/h staging, ~17.8 MB
    unsigned short* gxbf = ws + XBF_OFF;
    unsigned short* ghbf = ws + HBF_OFF;
    float*          gh   = (float*)(ws + H_OFF);

    hyper_prep_kernel<<<2488, 256, 0, stream>>>(x, cond, base_weight, base_bias,
                                                w1, b1, w2, b2, ws, gxbf, ghbf, gh, out);
    hyper_main_kernel<<<576, 256, 0, stream>>>(ws, gxbf, ghbf, gh, out);
}

// Round 7
// 121.246 us; speedup vs baseline: 1.0066x; 1.0066x over previous
//
#include <hip/hip_runtime.h>
#include <hip/hip_bf16.h>
#include <stdint.h>

#define BATCH    512
#define IN_DIM   256
#define OUT_DIM  256
#define COND_DIM 128
#define HIDDEN   128
#define W2_COLS  65792      // 256*257
#define H_STRIDE 132
#define PLANE_SZ 65536      // shorts per transposed bf16 plane [o][i]
#define OUT_ELEMS (BATCH * OUT_DIM)

// workspace layout (shorts unless noted):
//   [0, 130*PLANE_SZ)                     : transposed bf16 planes
//     planes 0..127 = w2 hidden-unit planes; 128 = base_weight + b2-weight
//     (folded, scale 1); 129 = bias-delta cols (A = h)
//   XBF_OFF : bf16 x   (BATCH*IN_DIM shorts)
//   HBF_OFF : bf16 h   (BATCH*HIDDEN shorts)
//   H_OFF   : f32 h    (BATCH*H_STRIDE+8 floats)
#define XBF_OFF  ((size_t)130 * PLANE_SZ)
#define HBF_OFF  (XBF_OFF + (size_t)BATCH * IN_DIM)
#define H_OFF    (HBF_OFF + (size_t)BATCH * HIDDEN)

typedef __attribute__((ext_vector_type(8))) short bf16x8;
typedef __attribute__((ext_vector_type(4))) float f32x4;

static __device__ __forceinline__ unsigned short f2bf(float f) {
    union { float f; unsigned int u; } v; v.f = f;
    unsigned int r = v.u + 0x7FFFu + ((v.u >> 16) & 1u);  // RNE
    return (unsigned short)(r >> 16);
}
static __device__ __forceinline__ unsigned int pack2(float a, float b) {
    return (unsigned int)f2bf(a) | ((unsigned int)f2bf(b) << 16);
}

template<int N>
static __device__ __forceinline__ void wait_vmcnt() {
    if constexpr (N == 0)      asm volatile("s_waitcnt vmcnt(0)" ::: "memory");
    else if constexpr (N == 2) asm volatile("s_waitcnt vmcnt(2)" ::: "memory");
    else if constexpr (N == 4) asm volatile("s_waitcnt vmcnt(4)" ::: "memory");
    else if constexpr (N == 6) asm volatile("s_waitcnt vmcnt(6)" ::: "memory");
    else                       asm volatile("s_waitcnt vmcnt(8)" ::: "memory");
}

// ---------------- prep: convert/transpose planes + x,h + out-init ----------
// grid: [0,2064) w2 planes + folded (bw+b2w) plane tiles;
//       [2064,2072) bias-delta col tiles (plane 129);
//       [2072,2088) x convert; [2088,2344) h compute (2 rows/block);
//       [2344,2472) out init = base_bias + b2_bias
__global__ __launch_bounds__(256)
void hyper_prep_kernel(const float* __restrict__ x,
                       const float* __restrict__ cond,
                       const float* __restrict__ base_weight,
                       const float* __restrict__ base_bias,
                       const float* __restrict__ w1,
                       const float* __restrict__ b1,
                       const float* __restrict__ w2,
                       const float* __restrict__ b2,
                       unsigned short* __restrict__ wt,
                       unsigned short* __restrict__ gxbf,
                       unsigned short* __restrict__ ghbf,
                       float* __restrict__ gh,
                       float* __restrict__ out) {
    const int bx = blockIdx.x;
    const int t  = threadIdx.x;
    if (bx < 2072) {
        int p, it, ot; const float* src; int rstride; bool addw = false;
        if (bx < 2064) {
            p = bx >> 4; int sub = bx & 15; it = sub >> 2; ot = sub & 3;
            src = (p < 128) ? (w2 + (size_t)p * W2_COLS) : b2;
            addw = (p == 128);                 // fold base_weight into plane 128
            rstride = OUT_DIM;
        } else {
            p = 129; int sub = bx - 2064; it = sub >> 2; ot = sub & 3;   // it 0..1
            src = w2 + 65536; rstride = W2_COLS;
        }
        int o  = ot * 64 + (t & 63);
        int i0 = it * 64 + (t >> 6) * 16;
        unsigned int vv[8];
        #pragma unroll
        for (int r = 0; r < 8; ++r) {
            size_t i1 = (size_t)(i0 + 2 * r)     * rstride + o;
            size_t i2 = (size_t)(i0 + 2 * r + 1) * rstride + o;
            float a = src[i1], b = src[i2];
            if (addw) { a += base_weight[i1]; b += base_weight[i2]; }
            vv[r] = pack2(a, b);
        }
        unsigned int* dst = (unsigned int*)(wt + (size_t)p * PLANE_SZ + (size_t)o * 256 + i0);
        *(uint4*)dst       = *(uint4*)&vv[0];
        *(uint4*)(dst + 4) = *(uint4*)&vv[4];
    } else if (bx < 2088) {
        int base = (bx - 2072) * 8192 + t * 32;
        #pragma unroll
        for (int g = 0; g < 4; ++g) {
            const float4* s4 = (const float4*)(x + base + g * 8);
            float4 a = s4[0], b = s4[1];
            unsigned int vv[4] = { pack2(a.x, a.y), pack2(a.z, a.w),
                                   pack2(b.x, b.y), pack2(b.z, b.w) };
            *(uint4*)(gxbf + base + g * 8) = *(uint4*)vv;
        }
    } else if (bx < 2344) {
        __shared__ float c[2][COND_DIM];
        int bb = t >> 7, k = t & 127;
        int b  = (bx - 2088) * 2 + bb;
        c[bb][k] = cond[b * COND_DIM + k];
        __syncthreads();
        float acc = b1[k];
        #pragma unroll 8
        for (int i = 0; i < COND_DIM; ++i)
            acc += c[bb][i] * w1[i * HIDDEN + k];
        acc = fmaxf(acc, 0.0f);
        gh[b * H_STRIDE + k] = acc;
        ghbf[b * HIDDEN + k] = f2bf(acc);
        if (k < 4) gh[b * H_STRIDE + 128 + k] = 1.0f;
    } else {
        // out init: out[b,o] = base_bias[o] + b2[65536+o]   (float4 granular)
        int i = (bx - 2344) * 256 + t;                 // float4 index, 32768 total
        int o = (i & 63) * 4;
        float4 bb = *(const float4*)(base_bias + o);
        float4 c2 = *(const float4*)(b2 + 65536 + o);
        float4 a;
        a.x = bb.x + c2.x; a.y = bb.y + c2.y; a.z = bb.z + c2.z; a.w = bb.w + c2.w;
        ((float4*)out)[i] = a;
    }
}

// ---------------- main: split-K MFMA GEMM, deep counted-vmcnt pipeline -----
// 4 waves (256 thr), 64x64 tile, 6 LDS buffers, DMA issued 5 steps ahead
// (10 loads in flight), steady s_waitcnt vmcnt(8), tail 6/4/2/0, ONE
// s_barrier per step. Refill target buffer (s+5)%6 == (s-1)%6 was consumed
// at step s-1; barrier(s) separates. Epilogue: f32 atomics into out.
template<int NSLABS>
static __device__ __forceinline__ void run_gemm(
    int nplanes, int p0, const unsigned short* asrc, int astride,
    const unsigned short* __restrict__ wt, float* __restrict__ out,
    int b0, int o0, int t,
    unsigned short (*B_lds)[64 * 64], const float* h_s)
{
    constexpr int LOG2S = (NSLABS == 4) ? 2 : 1;
    const int lane = t & 63, wave = t >> 6;
    const int wm = wave >> 1, wn = wave & 1;
    const int qg = lane >> 4, ncol = lane & 15;

    const int drow = lane >> 3;                  // 0..7
    const int dcol = ((lane & 7) ^ drow) * 8;    // swizzled k-block (shorts)
    const int nsteps = nplanes * NSLABS;

    auto dmaB = [&](int s, int buf) {
        const int plane = p0 + (s >> LOG2S);
        const int i0    = (s & (NSLABS - 1)) * 64;
        const unsigned short* gp = wt + (size_t)plane * PLANE_SZ
            + (size_t)(o0 + wave * 16 + drow) * 256 + i0 + dcol;
        __builtin_amdgcn_global_load_lds(
            (const __attribute__((address_space(1))) unsigned int*)gp,
            (__attribute__((address_space(3))) unsigned int*)&B_lds[buf][wave * 16 * 64],
            16, 0, 0);
        __builtin_amdgcn_global_load_lds(
            (const __attribute__((address_space(1))) unsigned int*)(gp + 8 * 256),
            (__attribute__((address_space(3))) unsigned int*)&B_lds[buf][(wave * 16 + 8) * 64],
            16, 0, 0);
    };

    // A fragments: loaded once (oldest VMEM ops -> retire before DMA waits)
    bf16x8 xf[NSLABS][2][2];
    #pragma unroll
    for (int sl = 0; sl < NSLABS; ++sl)
        #pragma unroll
        for (int ks = 0; ks < 2; ++ks)
            #pragma unroll
            for (int mf = 0; mf < 2; ++mf)
                xf[sl][ks][mf] = *(const bf16x8*)(asrc
                    + (size_t)(b0 + wm * 32 + mf * 16 + ncol) * astride
                    + sl * 64 + ks * 32 + qg * 8);

    f32x4 acc[2][2] = {};
    f32x4 pacc[2][2];
    float hv[2][4];

    // prologue: fill 5-deep pipeline
    #pragma unroll
    for (int s = 0; s < 5; ++s)
        if (s < nsteps) dmaB(s, s);

    int cur = 0, pre = 5;                        // running buffer indices mod 6

    for (int pl = 0; pl < nplanes; ++pl) {
        #pragma unroll
        for (int sl = 0; sl < NSLABS; ++sl) {
            const int s = pl * NSLABS + sl;

            if (sl == 0) {                       // h scales + pacc reset (pre-wait)
                #pragma unroll
                for (int mf = 0; mf < 2; ++mf)
                    #pragma unroll
                    for (int r = 0; r < 4; ++r)
                        hv[mf][r] = h_s[(wm * 32 + mf * 16 + qg * 4 + r) * 8 + pl];
                #pragma unroll
                for (int a = 0; a < 2; ++a)
                    #pragma unroll
                    for (int bq = 0; bq < 2; ++bq)
                        pacc[a][bq] = (f32x4){0.f, 0.f, 0.f, 0.f};
            }

            // wait only for THIS step's 2 loads (up to 8 newer stay in flight)
            if (s <= nsteps - 5)      wait_vmcnt<8>();
            else if (s == nsteps - 4) wait_vmcnt<6>();
            else if (s == nsteps - 3) wait_vmcnt<4>();
            else if (s == nsteps - 2) wait_vmcnt<2>();
            else                      wait_vmcnt<0>();
            __builtin_amdgcn_s_barrier();
            asm volatile("" ::: "memory");           // no LDS reads above barrier

            __builtin_amdgcn_s_setprio(1);
            #pragma unroll
            for (int ks = 0; ks < 2; ++ks) {
                bf16x8 bfr[2];
                #pragma unroll
                for (int nf = 0; nf < 2; ++nf) {
                    int n = wn * 32 + nf * 16 + ncol;
                    bfr[nf] = *(const bf16x8*)&B_lds[cur][(n * 8 + ((ks * 4 + qg) ^ (n & 7))) * 8];
                }
                #pragma unroll
                for (int mf = 0; mf < 2; ++mf)
                    #pragma unroll
                    for (int nf = 0; nf < 2; ++nf)
                        pacc[mf][nf] = __builtin_amdgcn_mfma_f32_16x16x32_bf16(
                            xf[sl][ks][mf], bfr[nf], pacc[mf][nf], 0, 0, 0);
            }
            __builtin_amdgcn_s_setprio(0);

            if (sl == NSLABS - 1) {              // fold plane into acc with h scale
                #pragma unroll
                for (int mf = 0; mf < 2; ++mf)
                    #pragma unroll
                    for (int nf = 0; nf < 2; ++nf)
                        #pragma unroll
                        for (int r = 0; r < 4; ++r)
                            acc[mf][nf][r] += hv[mf][r] * pacc[mf][nf][r];
            }

            // refill: buffer (s+5)%6 == (s-1)%6, consumed at step s-1;
            // all waves passed barrier(s) after finishing it -> safe
            if (s + 5 < nsteps) dmaB(s + 5, pre);
            cur = (cur == 5) ? 0 : cur + 1;
            pre = (pre == 5) ? 0 : pre + 1;
        }
    }

    // f32 atomic accumulate into out (hardware global_atomic_add_f32)
    #pragma unroll
    for (int mf = 0; mf < 2; ++mf)
        #pragma unroll
        for (int nf = 0; nf < 2; ++nf)
            #pragma unroll
            for (int r = 0; r < 4; ++r) {
                int row = b0 + wm * 32 + mf * 16 + qg * 4 + r;
                int col = o0 + wn * 32 + nf * 16 + ncol;
                unsafeAtomicAdd(&out[(size_t)row * OUT_DIM + col], acc[mf][nf][r]);
            }
}

__global__ __launch_bounds__(256, 3)
void hyper_main_kernel(const unsigned short* __restrict__ wt,
                       const unsigned short* __restrict__ gxbf,
                       const unsigned short* __restrict__ ghbf,
                       const float* __restrict__ gh,
                       float* __restrict__ out) {
    __shared__ __align__(16) unsigned short B_lds[6][64 * 64];   // 48 KB
    __shared__ float h_s[512];                                   // 64 rows x 8 planes

    // XCD co-location swizzle: the 8 batch-tiles sharing (chunk,o0) plane
    // slices all get bx%8 == G%8 -> same XCD under round-robin dispatch ->
    // plane slice fetched from LLC once/XCD, re-read from local 4MB L2.
    // Bijection: bx = (bt*9 + G/8)*8 + G%8, G = chunk*4 + ot in [0,72).
    const int bx  = blockIdx.x;              // 576 blocks
    const int low = bx & 7;
    const int q   = bx >> 3;                 // [0,72)
    const int bt  = q / 9;                   // batch-tile member [0,8)
    const int G   = (q % 9) * 8 + low;       // group [0,72)
    const int chunk = G >> 2;
    const int b0  = bt * 64;
    const int o0  = (G & 3) * 64;
    const int t   = threadIdx.x;

    const int p0 = (chunk < 16) ? chunk * 8 : (chunk == 16 ? 128 : 129);

    // stage per-plane h scales (chunks 16/17 read 1.0 from gh ones-lanes)
    h_s[t]       = gh[(b0      + (t >> 3)) * H_STRIDE + p0 + (t & 7)];
    h_s[256 + t] = gh[(b0 + 32 + (t >> 3)) * H_STRIDE + p0 + (t & 7)];
    __syncthreads();

    if (chunk < 17)
        run_gemm<4>(chunk < 16 ? 8 : 1, p0, gxbf, IN_DIM,
                    wt, out, b0, o0, t, B_lds, h_s);
    else
        run_gemm<2>(1, p0, ghbf, HIDDEN,
                    wt, out, b0, o0, t, B_lds, h_s);
}

// ---------------- launch ---------------------------------------------------
extern "C" void kernel_launch(void* const* d_in, const int* in_sizes, int n_in,
                              void* d_out, int out_size, void* d_ws, size_t ws_size,
                              hipStream_t stream) {
    const float* x           = (const float*)d_in[0];
    const float* cond        = (const float*)d_in[1];
    const float* base_weight = (const float*)d_in[2];
    const float* base_bias   = (const float*)d_in[3];
    const float* w1          = (const float*)d_in[4];
    const float* b1          = (const float*)d_in[5];
    const float* w2          = (const float*)d_in[6];
    const float* b2          = (const float*)d_in[7];
    float* out = (float*)d_out;

    unsigned short* ws   = (unsigned short*)d_ws;   // planes + x/h staging, ~17.7 MB
    unsigned short* gxbf = ws + XBF_OFF;
    unsigned short* ghbf = ws + HBF_OFF;
    float*          gh   = (float*)(ws + H_OFF);

    hyper_prep_kernel<<<2472, 256, 0, stream>>>(x, cond, base_weight, base_bias,
                                                w1, b1, w2, b2, ws, gxbf, ghbf, gh, out);
    hyper_main_kernel<<<576, 256, 0, stream>>>(ws, gxbf, ghbf, gh, out);
}